// Round 1
// baseline (1984.393 us; speedup 1.0000x reference)
//
#include <hip/hip_runtime.h>

#define NN 50000
#define EE 800000
#define HH 4

// ---------------- GEMM: C[M,N] = A[M,K] @ B  (+bias, +leakyrelu) -------------
// BT=false: B is [K,N] row-major.  BT=true: B is [N,K] row-major (B^T matmul).
template<bool BT, bool ACT>
__global__ __launch_bounds__(256) void gemm_k(
    const float* __restrict__ A, const float* __restrict__ B,
    const float* __restrict__ bias, float* __restrict__ C,
    int M, int N, int K, float slope)
{
    __shared__ float As[32][68];
    __shared__ float Bs[32][68];
    const int t  = threadIdx.x;
    const int tn = t & 15;
    const int tm = t >> 4;
    const int m0 = blockIdx.y * 64;
    const int n0 = blockIdx.x * 64;

    float acc[4][4] = {};

    const int arow = t >> 3;          // 0..31 (A/Bt loader: 64 rows x 32 cols)
    const int acol = (t & 7) * 4;
    const int brow = t >> 4;          // 0..15 (B loader: 32 rows x 64 cols)
    const int bcol = (t & 15) * 4;

    for (int k0 = 0; k0 < K; k0 += 32) {
        #pragma unroll
        for (int rr = 0; rr < 2; ++rr) {
            int row = arow + rr * 32;
            int gm  = m0 + row;
            float4 v = make_float4(0.f, 0.f, 0.f, 0.f);
            if (gm < M)
                v = *reinterpret_cast<const float4*>(&A[(size_t)gm * K + k0 + acol]);
            As[acol + 0][row] = v.x;
            As[acol + 1][row] = v.y;
            As[acol + 2][row] = v.z;
            As[acol + 3][row] = v.w;
        }
        if (!BT) {
            #pragma unroll
            for (int rr = 0; rr < 2; ++rr) {
                int row = brow + rr * 16;   // k within tile
                float4 v = *reinterpret_cast<const float4*>(
                    &B[(size_t)(k0 + row) * N + n0 + bcol]);
                *reinterpret_cast<float4*>(&Bs[row][bcol]) = v;
            }
        } else {
            #pragma unroll
            for (int rr = 0; rr < 2; ++rr) {
                int row = arow + rr * 32;   // n within tile
                float4 v = *reinterpret_cast<const float4*>(
                    &B[(size_t)(n0 + row) * K + k0 + acol]);
                Bs[acol + 0][row] = v.x;
                Bs[acol + 1][row] = v.y;
                Bs[acol + 2][row] = v.z;
                Bs[acol + 3][row] = v.w;
            }
        }
        __syncthreads();
        #pragma unroll
        for (int k = 0; k < 32; ++k) {
            float4 a = *reinterpret_cast<const float4*>(&As[k][tm * 4]);
            float4 b = *reinterpret_cast<const float4*>(&Bs[k][tn * 4]);
            float av[4] = {a.x, a.y, a.z, a.w};
            float bv[4] = {b.x, b.y, b.z, b.w};
            #pragma unroll
            for (int i = 0; i < 4; ++i)
                #pragma unroll
                for (int j = 0; j < 4; ++j)
                    acc[i][j] = fmaf(av[i], bv[j], acc[i][j]);
        }
        __syncthreads();
    }

    #pragma unroll
    for (int i = 0; i < 4; ++i) {
        int gm = m0 + tm * 4 + i;
        if (gm >= M) break;
        #pragma unroll
        for (int j = 0; j < 4; ++j) {
            int gn = n0 + tn * 4 + j;
            float v = acc[i][j];
            if (ACT) {
                v += bias[gn];
                v = v >= 0.f ? v : slope * v;
            }
            C[(size_t)gm * N + gn] = v;
        }
    }
}

// --------------- el/er: per (n,h) dot(z, attn_l), dot(z, attn_r) -------------
template<int D>
__global__ __launch_bounds__(256) void elr_k(
    const float* __restrict__ z, const float* __restrict__ al,
    const float* __restrict__ ar, float* __restrict__ el,
    float* __restrict__ er)
{
    int wid  = blockIdx.x * 4 + (threadIdx.x >> 6);
    if (wid >= NN * HH) return;
    int lane = threadIdx.x & 63;
    int h = wid & 3;
    const float* zp  = z + (size_t)wid * D;
    const float* alp = al + h * D;
    const float* arp = ar + h * D;
    float sl = zp[lane] * alp[lane];
    float sr = zp[lane] * arp[lane];
    if (D == 128) {
        sl += zp[lane + 64] * alp[lane + 64];
        sr += zp[lane + 64] * arp[lane + 64];
    }
    #pragma unroll
    for (int o = 32; o; o >>= 1) {
        sl += __shfl_xor(sl, o);
        sr += __shfl_xor(sr, o);
    }
    if (lane == 0) { el[wid] = sl; er[wid] = sr; }
}

// --------------- CSR build ---------------------------------------------------
__global__ void hist_k(const int* __restrict__ dst, int* __restrict__ cnt)
{
    int i = blockIdx.x * blockDim.x + threadIdx.x;
    if (i < EE) atomicAdd(&cnt[dst[i]], 1);
}

__global__ __launch_bounds__(1024) void scan_k(const int* __restrict__ cnt,
                                               int* __restrict__ offs)
{
    __shared__ int part[1024];
    int t = threadIdx.x;
    const int per = (NN + 1023) / 1024;
    int beg = t * per, end = min(beg + per, NN);
    int sum = 0;
    for (int i = beg; i < end; ++i) sum += cnt[i];
    part[t] = sum;
    __syncthreads();
    for (int off = 1; off < 1024; off <<= 1) {
        int add = (t >= off) ? part[t - off] : 0;
        __syncthreads();
        part[t] += add;
        __syncthreads();
    }
    int run = (t == 0) ? 0 : part[t - 1];
    for (int i = beg; i < end; ++i) { offs[i] = run; run += cnt[i]; }
    if (t == 0) offs[NN] = part[1023];
}

__global__ void scatter_k(const int* __restrict__ src, const int* __restrict__ dst,
                          const int* __restrict__ offs, int* __restrict__ cursor,
                          int* __restrict__ srcs_sorted)
{
    int i = blockIdx.x * blockDim.x + threadIdx.x;
    if (i >= EE) return;
    int d = dst[i];
    int p = offs[d] + atomicAdd(&cursor[d], 1);
    srcs_sorted[p] = src[i];
}

// --------------- GAT aggregation: one wave per (dst node, head) --------------
template<int D>
__global__ __launch_bounds__(256) void agg_k(
    const float* __restrict__ z, const float* __restrict__ el,
    const float* __restrict__ er, const int* __restrict__ offs,
    const int* __restrict__ srcs, const float* __restrict__ bias,
    float* __restrict__ out)
{
    int wid = blockIdx.x * 4 + (threadIdx.x >> 6);
    if (wid >= NN * HH) return;
    int lane = threadIdx.x & 63;
    int n = wid >> 2, h = wid & 3;
    int beg = offs[n], end = offs[n + 1];
    float ern = er[n * HH + h];

    float m = -1e30f;
    for (int e = beg; e < end; ++e) {
        float x = el[srcs[e] * HH + h] + ern;
        x = x >= 0.f ? x : 0.2f * x;
        m = fmaxf(m, x);
    }
    float acc0 = 0.f, acc1 = 0.f, wsum = 0.f;
    for (int e = beg; e < end; ++e) {
        int s = srcs[e];
        float x = el[s * HH + h] + ern;
        x = x >= 0.f ? x : 0.2f * x;
        float ex = __expf(x - m);
        wsum += ex;
        const float* zp = z + ((size_t)s * HH + h) * D;
        acc0 = fmaf(ex, zp[lane], acc0);
        if (D == 128) acc1 = fmaf(ex, zp[lane + 64], acc1);
    }
    float inv = wsum > 0.f ? 1.f / wsum : 0.f;
    float* op = out + ((size_t)n * HH + h) * D;
    float v0 = acc0 * inv + bias[h * D + lane];
    v0 = v0 >= 0.f ? v0 : 0.01f * v0;
    op[lane] = v0;
    if (D == 128) {
        float v1 = acc1 * inv + bias[h * D + lane + 64];
        v1 = v1 >= 0.f ? v1 : 0.01f * v1;
        op[lane + 64] = v1;
    }
}

// --------------- head mean + final activation --------------------------------
__global__ void mean_k(const float* __restrict__ g, float* __restrict__ out)
{
    int i = blockIdx.x * blockDim.x + threadIdx.x;
    if (i >= NN * 64) return;
    int n = i >> 6, d = i & 63;
    const float* gp = g + (size_t)n * 256;
    float s = (gp[d] + gp[64 + d] + gp[128 + d] + gp[192 + d]) * 0.25f;
    out[i] = s >= 0.f ? s : 0.01f * s;
}

// -----------------------------------------------------------------------------
extern "C" void kernel_launch(void* const* d_in, const int* in_sizes, int n_in,
                              void* d_out, int out_size, void* d_ws, size_t ws_size,
                              hipStream_t stream)
{
    const float* n_feat = (const float*)d_in[0];
    const int*   src    = (const int*)d_in[1];
    const int*   dst    = (const int*)d_in[2];
    const float* g0_W  = (const float*)d_in[3];
    const float* g0_al = (const float*)d_in[4];
    const float* g0_ar = (const float*)d_in[5];
    const float* g0_b  = (const float*)d_in[6];
    const float* d0_W  = (const float*)d_in[7];
    const float* d0_b  = (const float*)d_in[8];
    const float* g1_W  = (const float*)d_in[9];
    const float* g1_al = (const float*)d_in[10];
    const float* g1_ar = (const float*)d_in[11];
    const float* g1_b  = (const float*)d_in[12];
    const float* d1_W  = (const float*)d_in[13];
    const float* d1_b  = (const float*)d_in[14];
    const float* g2_W  = (const float*)d_in[15];
    const float* g2_al = (const float*)d_in[16];
    const float* g2_ar = (const float*)d_in[17];
    const float* g2_b  = (const float*)d_in[18];

    char* ws = (char*)d_ws;
    size_t off = 0;
    auto alloc = [&](size_t bytes) {
        void* p = ws + off;
        off += (bytes + 255) & ~(size_t)255;
        return p;
    };
    float* zA   = (float*)alloc((size_t)NN * 512 * 4);
    float* hB   = (float*)alloc((size_t)NN * 512 * 4);
    float* hC   = (float*)alloc((size_t)NN * 128 * 4);
    float* el   = (float*)alloc((size_t)NN * HH * 4);
    float* er   = (float*)alloc((size_t)NN * HH * 4);
    int*   cnt  = (int*)alloc((size_t)NN * 4);
    int*   curs = (int*)alloc((size_t)NN * 4);
    int*   offs = (int*)alloc((size_t)(NN + 1) * 4);
    int*   srcs = (int*)alloc((size_t)EE * 4);

    // ---- CSR build (per call; deterministic inputs) ----
    hipMemsetAsync(cnt, 0, (size_t)NN * 4, stream);
    hipMemsetAsync(curs, 0, (size_t)NN * 4, stream);
    hist_k<<<(EE + 255) / 256, 256, 0, stream>>>(dst, cnt);
    scan_k<<<1, 1024, 0, stream>>>(cnt, offs);
    scatter_k<<<(EE + 255) / 256, 256, 0, stream>>>(src, dst, offs, curs, srcs);

    const int MT = (NN + 63) / 64;       // 782 row tiles
    const int WAVB = (NN * HH + 3) / 4;  // 50000 blocks, 4 waves each

    // ---- layer 0: GAT(128 -> 4x128) + dense ----
    gemm_k<false, false><<<dim3(8, MT), 256, 0, stream>>>(
        n_feat, g0_W, nullptr, zA, NN, 512, 128, 0.f);
    elr_k<128><<<WAVB, 256, 0, stream>>>(zA, g0_al, g0_ar, el, er);
    agg_k<128><<<WAVB, 256, 0, stream>>>(zA, el, er, offs, srcs, g0_b, hB);
    gemm_k<true, true><<<dim3(2, MT), 256, 0, stream>>>(
        hB, d0_W, d0_b, hC, NN, 128, 512, 0.01f);

    // ---- layer 1: GAT(128 -> 4x128) + dense ----
    gemm_k<false, false><<<dim3(8, MT), 256, 0, stream>>>(
        hC, g1_W, nullptr, zA, NN, 512, 128, 0.f);
    elr_k<128><<<WAVB, 256, 0, stream>>>(zA, g1_al, g1_ar, el, er);
    agg_k<128><<<WAVB, 256, 0, stream>>>(zA, el, er, offs, srcs, g1_b, hB);
    gemm_k<true, true><<<dim3(2, MT), 256, 0, stream>>>(
        hB, d1_W, d1_b, hC, NN, 128, 512, 0.01f);

    // ---- layer 2: GAT(128 -> 4x64) + mean ----
    gemm_k<false, false><<<dim3(4, MT), 256, 0, stream>>>(
        hC, g2_W, nullptr, zA, NN, 256, 128, 0.f);
    elr_k<64><<<WAVB, 256, 0, stream>>>(zA, g2_al, g2_ar, el, er);
    agg_k<64><<<WAVB, 256, 0, stream>>>(zA, el, er, offs, srcs, g2_b, hB);
    mean_k<<<(NN * 64 + 255) / 256, 256, 0, stream>>>(hB, (float*)d_out);
}

// Round 3
// 1137.296 us; speedup vs baseline: 1.7448x; 1.7448x over previous
//
#include <hip/hip_runtime.h>

#define NN 50000
#define EE 800000
#define HH 4

typedef __attribute__((ext_vector_type(8))) unsigned short ushort8v;
typedef __attribute__((ext_vector_type(4))) unsigned short ushort4v;

__device__ __forceinline__ float b2f(unsigned short u) {
    return __uint_as_float(((unsigned int)u) << 16);
}
__device__ __forceinline__ unsigned short f2b(float f) {
    unsigned int x = __float_as_uint(f);
    x += 0x7fffu + ((x >> 16) & 1u);
    return (unsigned short)(x >> 16);
}

// ---------------- GEMM: C[M,N] = A[M,K] @ B  (+bias, +leakyrelu) -------------
// BT=false: B is [K,N] row-major.  BT=true: B is [N,K] row-major (B^T matmul).
// WB: also write a bf16 copy of C (pre-activation z) for the gather path.
template<bool BT, bool ACT, bool WB>
__global__ __launch_bounds__(256) void gemm_k(
    const float* __restrict__ A, const float* __restrict__ B,
    const float* __restrict__ bias, float* __restrict__ C,
    unsigned short* __restrict__ Cb,
    int M, int N, int K, float slope)
{
    __shared__ float As[32][68];
    __shared__ float Bs[32][68];
    const int t  = threadIdx.x;
    const int tn = t & 15;
    const int tm = t >> 4;
    const int m0 = blockIdx.y * 64;
    const int n0 = blockIdx.x * 64;

    float acc[4][4] = {};

    const int arow = t >> 3;          // 0..31 (A/Bt loader: 64 rows x 32 cols)
    const int acol = (t & 7) * 4;
    const int brow = t >> 4;          // 0..15 (B loader: 32 rows x 64 cols)
    const int bcol = (t & 15) * 4;

    for (int k0 = 0; k0 < K; k0 += 32) {
        #pragma unroll
        for (int rr = 0; rr < 2; ++rr) {
            int row = arow + rr * 32;
            int gm  = m0 + row;
            float4 v = make_float4(0.f, 0.f, 0.f, 0.f);
            if (gm < M)
                v = *reinterpret_cast<const float4*>(&A[(size_t)gm * K + k0 + acol]);
            As[acol + 0][row] = v.x;
            As[acol + 1][row] = v.y;
            As[acol + 2][row] = v.z;
            As[acol + 3][row] = v.w;
        }
        if (!BT) {
            #pragma unroll
            for (int rr = 0; rr < 2; ++rr) {
                int row = brow + rr * 16;   // k within tile
                float4 v = *reinterpret_cast<const float4*>(
                    &B[(size_t)(k0 + row) * N + n0 + bcol]);
                *reinterpret_cast<float4*>(&Bs[row][bcol]) = v;
            }
        } else {
            #pragma unroll
            for (int rr = 0; rr < 2; ++rr) {
                int row = arow + rr * 32;   // n within tile
                float4 v = *reinterpret_cast<const float4*>(
                    &B[(size_t)(n0 + row) * K + k0 + acol]);
                Bs[acol + 0][row] = v.x;
                Bs[acol + 1][row] = v.y;
                Bs[acol + 2][row] = v.z;
                Bs[acol + 3][row] = v.w;
            }
        }
        __syncthreads();
        #pragma unroll
        for (int k = 0; k < 32; ++k) {
            float4 a = *reinterpret_cast<const float4*>(&As[k][tm * 4]);
            float4 b = *reinterpret_cast<const float4*>(&Bs[k][tn * 4]);
            float av[4] = {a.x, a.y, a.z, a.w};
            float bv[4] = {b.x, b.y, b.z, b.w};
            #pragma unroll
            for (int i = 0; i < 4; ++i)
                #pragma unroll
                for (int j = 0; j < 4; ++j)
                    acc[i][j] = fmaf(av[i], bv[j], acc[i][j]);
        }
        __syncthreads();
    }

    #pragma unroll
    for (int i = 0; i < 4; ++i) {
        int gm = m0 + tm * 4 + i;
        if (gm >= M) break;
        float vv[4];
        #pragma unroll
        for (int j = 0; j < 4; ++j) {
            int gn = n0 + tn * 4 + j;
            float v = acc[i][j];
            if (ACT) {
                v += bias[gn];
                v = v >= 0.f ? v : slope * v;
            }
            vv[j] = v;
        }
        float4 cv = make_float4(vv[0], vv[1], vv[2], vv[3]);
        *reinterpret_cast<float4*>(&C[(size_t)gm * N + n0 + tn * 4]) = cv;
        if (WB) {
            ushort4v ub;
            #pragma unroll
            for (int j = 0; j < 4; ++j) ub[j] = f2b(vv[j]);
            *reinterpret_cast<ushort4v*>(&Cb[(size_t)gm * N + n0 + tn * 4]) = ub;
        }
    }
}

// --------------- el/er: per (n,h) dot(z, attn_l), dot(z, attn_r) -------------
template<int D>
__global__ __launch_bounds__(256) void elr_k(
    const float* __restrict__ z, const float* __restrict__ al,
    const float* __restrict__ ar, float* __restrict__ el,
    float* __restrict__ er)
{
    int wid  = blockIdx.x * 4 + (threadIdx.x >> 6);
    if (wid >= NN * HH) return;
    int lane = threadIdx.x & 63;
    int h = wid & 3;
    const float* zp  = z + (size_t)wid * D;
    const float* alp = al + h * D;
    const float* arp = ar + h * D;
    float sl = zp[lane] * alp[lane];
    float sr = zp[lane] * arp[lane];
    if (D == 128) {
        sl += zp[lane + 64] * alp[lane + 64];
        sr += zp[lane + 64] * arp[lane + 64];
    }
    #pragma unroll
    for (int o = 32; o; o >>= 1) {
        sl += __shfl_xor(sl, o);
        sr += __shfl_xor(sr, o);
    }
    if (lane == 0) { el[wid] = sl; er[wid] = sr; }
}

// --------------- CSR build ---------------------------------------------------
__global__ void hist_k(const int* __restrict__ dst, int* __restrict__ cnt)
{
    int i = blockIdx.x * blockDim.x + threadIdx.x;
    if (i < EE) atomicAdd(&cnt[dst[i]], 1);
}

__global__ __launch_bounds__(1024) void scan_k(const int* __restrict__ cnt,
                                               int* __restrict__ offs)
{
    __shared__ int part[1024];
    int t = threadIdx.x;
    const int per = (NN + 1023) / 1024;
    int beg = t * per, end = min(beg + per, NN);
    int sum = 0;
    for (int i = beg; i < end; ++i) sum += cnt[i];
    part[t] = sum;
    __syncthreads();
    for (int off = 1; off < 1024; off <<= 1) {
        int add = (t >= off) ? part[t - off] : 0;
        __syncthreads();
        part[t] += add;
        __syncthreads();
    }
    int run = (t == 0) ? 0 : part[t - 1];
    for (int i = beg; i < end; ++i) { offs[i] = run; run += cnt[i]; }
    if (t == 0) offs[NN] = part[1023];
}

__global__ void scatter_k(const int* __restrict__ src, const int* __restrict__ dst,
                          const int* __restrict__ offs, int* __restrict__ cursor,
                          int* __restrict__ srcs_sorted)
{
    int i = blockIdx.x * blockDim.x + threadIdx.x;
    if (i >= EE) return;
    int d = dst[i];
    int p = offs[d] + atomicAdd(&cursor[d], 1);
    srcs_sorted[p] = src[i];
}

// --------------- GAT aggregation: one wave per dst node, ALL heads -----------
// zb: bf16 [N][H*D].  Lane l covers elements l*EPL .. l*EPL+EPL-1 of the row
// (head = l>>4).  MEAN: fuse bias+lrelu+head-mean+lrelu, write [N][D] to out.
template<int D, bool MEAN>
__global__ __launch_bounds__(256) void agg2_k(
    const unsigned short* __restrict__ zb, const float* __restrict__ el,
    const float* __restrict__ er, const int* __restrict__ offs,
    const int* __restrict__ srcs, const float* __restrict__ bias,
    float* __restrict__ out)
{
    constexpr int HD  = HH * D;
    constexpr int EPL = HD / 64;          // 8 for D=128, 4 for D=64
    int n = blockIdx.x * 4 + (threadIdx.x >> 6);
    if (n >= NN) return;
    int lane = threadIdx.x & 63;
    int h = lane >> 4;
    int beg = offs[n], end = offs[n + 1];
    float erh = er[n * HH + h];

    float m = -1e30f;
    for (int e = beg; e < end; ++e) {
        float x = el[srcs[e] * HH + h] + erh;
        x = x >= 0.f ? x : 0.2f * x;
        m = fmaxf(m, x);
    }

    float acc[EPL] = {};
    float wsum = 0.f;
    for (int e = beg; e < end; ++e) {
        int s = srcs[e];
        float x = el[s * HH + h] + erh;
        x = x >= 0.f ? x : 0.2f * x;
        float ex = __expf(x - m);
        wsum += ex;
        if (D == 128) {
            ushort8v v = *reinterpret_cast<const ushort8v*>(
                &zb[(size_t)s * HD + lane * EPL]);
            #pragma unroll
            for (int j = 0; j < EPL; ++j)
                acc[j] = fmaf(ex, b2f(v[j]), acc[j]);
        } else {
            ushort4v v = *reinterpret_cast<const ushort4v*>(
                &zb[(size_t)s * HD + lane * EPL]);
            #pragma unroll
            for (int j = 0; j < EPL; ++j)
                acc[j] = fmaf(ex, b2f(v[j]), acc[j]);
        }
    }
    float inv = wsum > 0.f ? 1.f / wsum : 0.f;

    float vv[EPL];
    #pragma unroll
    for (int j = 0; j < EPL; ++j) {
        float v = acc[j] * inv + bias[h * D + (lane & 15) * EPL + j];
        vv[j] = v >= 0.f ? v : 0.01f * v;
    }

    if (!MEAN) {
        float* op = out + (size_t)n * HD + lane * EPL;
        #pragma unroll
        for (int j = 0; j < EPL; j += 4)
            *reinterpret_cast<float4*>(op + j) =
                make_float4(vv[j], vv[j + 1], vv[j + 2], vv[j + 3]);
    } else {
        // head-mean: element d of head h lives at lane (h*16 + d/EPL), slot d%EPL
        #pragma unroll
        for (int j = 0; j < EPL; ++j) {
            float s = vv[j];
            s += __shfl_xor(s, 16);
            s += __shfl_xor(s, 32);
            s *= 0.25f;
            vv[j] = s >= 0.f ? s : 0.01f * s;
        }
        if (lane < 16) {
            float* op = out + (size_t)n * D + lane * EPL;
            #pragma unroll
            for (int j = 0; j < EPL; j += 4)
                *reinterpret_cast<float4*>(op + j) =
                    make_float4(vv[j], vv[j + 1], vv[j + 2], vv[j + 3]);
        }
    }
}

// -----------------------------------------------------------------------------
extern "C" void kernel_launch(void* const* d_in, const int* in_sizes, int n_in,
                              void* d_out, int out_size, void* d_ws, size_t ws_size,
                              hipStream_t stream)
{
    const float* n_feat = (const float*)d_in[0];
    const int*   src    = (const int*)d_in[1];
    const int*   dst    = (const int*)d_in[2];
    const float* g0_W  = (const float*)d_in[3];
    const float* g0_al = (const float*)d_in[4];
    const float* g0_ar = (const float*)d_in[5];
    const float* g0_b  = (const float*)d_in[6];
    const float* d0_W  = (const float*)d_in[7];
    const float* d0_b  = (const float*)d_in[8];
    const float* g1_W  = (const float*)d_in[9];
    const float* g1_al = (const float*)d_in[10];
    const float* g1_ar = (const float*)d_in[11];
    const float* g1_b  = (const float*)d_in[12];
    const float* d1_W  = (const float*)d_in[13];
    const float* d1_b  = (const float*)d_in[14];
    const float* g2_W  = (const float*)d_in[15];
    const float* g2_al = (const float*)d_in[16];
    const float* g2_ar = (const float*)d_in[17];
    const float* g2_b  = (const float*)d_in[18];

    char* ws = (char*)d_ws;
    size_t off = 0;
    auto alloc = [&](size_t bytes) {
        void* p = ws + off;
        off += (bytes + 255) & ~(size_t)255;
        return p;
    };
    // Workspace budget: round-1's 236 MB worked, round-2's 287 MB crashed.
    // Alias the agg output onto zA (fp32 z is dead once elr_k has consumed it):
    // total now ~185 MB.
    float*          zA   = (float*)alloc((size_t)NN * 512 * 4);   // fp32 z, then agg out
    unsigned short* zB16 = (unsigned short*)alloc((size_t)NN * 512 * 2);
    float*          hC   = (float*)alloc((size_t)NN * 128 * 4);
    float*          el   = (float*)alloc((size_t)NN * HH * 4);
    float*          er   = (float*)alloc((size_t)NN * HH * 4);
    int*            cnt  = (int*)alloc((size_t)NN * 4);
    int*            curs = (int*)alloc((size_t)NN * 4);
    int*            offs = (int*)alloc((size_t)(NN + 1) * 4);
    int*            srcs = (int*)alloc((size_t)EE * 4);
    float*          hB   = zA;   // alias: agg output overwrites fp32 z

    // ---- CSR build (per call; deterministic inputs) ----
    hipMemsetAsync(cnt, 0, (size_t)NN * 4, stream);
    hipMemsetAsync(curs, 0, (size_t)NN * 4, stream);
    hist_k<<<(EE + 255) / 256, 256, 0, stream>>>(dst, cnt);
    scan_k<<<1, 1024, 0, stream>>>(cnt, offs);
    scatter_k<<<(EE + 255) / 256, 256, 0, stream>>>(src, dst, offs, curs, srcs);

    const int MT    = (NN + 63) / 64;       // 782 row tiles
    const int WAVB  = (NN * HH + 3) / 4;    // (n,h) waves, 4 per block
    const int NODB  = (NN + 3) / 4;         // node waves, 4 per block

    // ---- layer 0: GAT(128 -> 4x128) + dense ----
    gemm_k<false, false, true><<<dim3(8, MT), 256, 0, stream>>>(
        n_feat, g0_W, nullptr, zA, zB16, NN, 512, 128, 0.f);
    elr_k<128><<<WAVB, 256, 0, stream>>>(zA, g0_al, g0_ar, el, er);
    agg2_k<128, false><<<NODB, 256, 0, stream>>>(zB16, el, er, offs, srcs, g0_b, hB);
    gemm_k<true, true, false><<<dim3(2, MT), 256, 0, stream>>>(
        hB, d0_W, d0_b, hC, nullptr, NN, 128, 512, 0.01f);

    // ---- layer 1: GAT(128 -> 4x128) + dense ----
    gemm_k<false, false, true><<<dim3(8, MT), 256, 0, stream>>>(
        hC, g1_W, nullptr, zA, zB16, NN, 512, 128, 0.f);
    elr_k<128><<<WAVB, 256, 0, stream>>>(zA, g1_al, g1_ar, el, er);
    agg2_k<128, false><<<NODB, 256, 0, stream>>>(zB16, el, er, offs, srcs, g1_b, hB);
    gemm_k<true, true, false><<<dim3(2, MT), 256, 0, stream>>>(
        hB, d1_W, d1_b, hC, nullptr, NN, 128, 512, 0.01f);

    // ---- layer 2: GAT(128 -> 4x64) + fused bias/lrelu/mean/lrelu ----
    gemm_k<false, false, true><<<dim3(4, MT), 256, 0, stream>>>(
        hC, g2_W, nullptr, zA, zB16, NN, 256, 128, 0.f);
    elr_k<64><<<WAVB, 256, 0, stream>>>(zA, g2_al, g2_ar, el, er);
    agg2_k<64, true><<<NODB, 256, 0, stream>>>(zB16, el, er, offs, srcs, g2_b,
                                               (float*)d_out);
}

// Round 4
// 719.385 us; speedup vs baseline: 2.7585x; 1.5809x over previous
//
#include <hip/hip_runtime.h>

#define NN 50000
#define EE 800000
#define HH 4

typedef __attribute__((ext_vector_type(8))) short short8v;     // 8 bf16 = 4 VGPR
typedef __attribute__((ext_vector_type(4))) float f32x4;
typedef __attribute__((ext_vector_type(8))) unsigned short ushort8v;
typedef __attribute__((ext_vector_type(4))) unsigned short ushort4v;

__device__ __forceinline__ float b2f(unsigned short u) {
    return __uint_as_float(((unsigned int)u) << 16);
}
__device__ __forceinline__ unsigned short f2b(float f) {
    unsigned int x = __float_as_uint(f);
    x += 0x7fffu + ((x >> 16) & 1u);
    return (unsigned short)(x >> 16);
}

// ---------------- bf16 MFMA GEMM: C[M,N] = A[M,K] @ Bt[N,K]^T ---------------
// A, Bt bf16 row-major.  Out bf16 (optionally +bias +leakyrelu).
// BM=64, BN=128, BK=32; 256 threads = 4 waves; wave w owns rows w*16..w*16+15.
template<bool ACT>
__global__ __launch_bounds__(256) void mgemm_k(
    const unsigned short* __restrict__ A, const unsigned short* __restrict__ Bt,
    const float* __restrict__ bias, unsigned short* __restrict__ C,
    int M, int N, int K, float slope)
{
    __shared__ unsigned short As[64 * 40];    // 40 = 32 + 8 pad (16B-aligned rows)
    __shared__ unsigned short Bs[128 * 40];
    const int t   = threadIdx.x;
    const int m0  = blockIdx.y * 64;
    const int n0  = blockIdx.x * 128;
    const int w16 = (t >> 6) * 16;
    const int l   = t & 63;
    const int lr  = l & 15;            // frag row (A) / col (B,C)
    const int lk8 = (l >> 4) * 8;      // frag k-offset

    f32x4 acc[8];
    #pragma unroll
    for (int i = 0; i < 8; ++i) acc[i] = (f32x4)0.f;

    const int arow = t >> 2, aseg = (t & 3) * 8;

    for (int k0 = 0; k0 < K; k0 += 32) {
        {   // stage A: 64 rows x 32 bf16, one 16B chunk per thread
            int gm = m0 + arow;
            short8v v = (short8v)0;
            if (gm < M)
                v = *reinterpret_cast<const short8v*>(&A[(size_t)gm * K + k0 + aseg]);
            *reinterpret_cast<short8v*>(&As[arow * 40 + aseg]) = v;
        }
        #pragma unroll
        for (int cc = 0; cc < 2; ++cc) {   // stage B: 128 rows x 32 bf16
            int c = t + cc * 256;
            int brow = c >> 2, bseg = (c & 3) * 8;
            short8v v = *reinterpret_cast<const short8v*>(
                &Bt[(size_t)(n0 + brow) * K + k0 + bseg]);
            *reinterpret_cast<short8v*>(&Bs[brow * 40 + bseg]) = v;
        }
        __syncthreads();
        short8v a = *reinterpret_cast<const short8v*>(&As[(w16 + lr) * 40 + lk8]);
        #pragma unroll
        for (int nb = 0; nb < 8; ++nb) {
            short8v b = *reinterpret_cast<const short8v*>(&Bs[(nb * 16 + lr) * 40 + lk8]);
            acc[nb] = __builtin_amdgcn_mfma_f32_16x16x32_bf16(a, b, acc[nb], 0, 0, 0);
        }
        __syncthreads();
    }

    #pragma unroll
    for (int nb = 0; nb < 8; ++nb) {
        #pragma unroll
        for (int r = 0; r < 4; ++r) {
            int gm = m0 + w16 + (l >> 4) * 4 + r;
            int gn = n0 + nb * 16 + lr;
            if (gm < M) {
                float v = acc[nb][r];
                if (ACT) { v += bias[gn]; v = v >= 0.f ? v : slope * v; }
                C[(size_t)gm * N + gn] = f2b(v);
            }
        }
    }
}

// ---------------- weight prep: transpose-cast / cast -------------------------
__global__ void tr_k(const float* __restrict__ W, unsigned short* __restrict__ Wt,
                     int K, int N)
{
    int idx = blockIdx.x * blockDim.x + threadIdx.x;
    if (idx >= K * N) return;
    int n = idx / K, k = idx - n * K;
    Wt[idx] = f2b(W[(size_t)k * N + n]);
}

__global__ void cast_k(const float* __restrict__ x, unsigned short* __restrict__ y,
                       int n4)
{
    int i = blockIdx.x * blockDim.x + threadIdx.x;
    if (i >= n4) return;
    float4 v = reinterpret_cast<const float4*>(x)[i];
    ushort4v u;
    u[0] = f2b(v.x); u[1] = f2b(v.y); u[2] = f2b(v.z); u[3] = f2b(v.w);
    reinterpret_cast<ushort4v*>(y)[i] = u;
}

// --------------- el/er from bf16 z -------------------------------------------
template<int D>
__global__ __launch_bounds__(256) void elrb_k(
    const unsigned short* __restrict__ zb, const float* __restrict__ al,
    const float* __restrict__ ar, float* __restrict__ el, float* __restrict__ er)
{
    int wid = blockIdx.x * 4 + (threadIdx.x >> 6);
    if (wid >= NN * HH) return;
    int lane = threadIdx.x & 63;
    int n = wid >> 2, h = wid & 3;
    const unsigned short* zp = zb + (size_t)n * (HH * D) + h * D;
    const float* alp = al + h * D;
    const float* arp = ar + h * D;
    float sl, sr;
    if (D == 128) {
        unsigned int u = *reinterpret_cast<const unsigned int*>(&zp[lane * 2]);
        float f0 = b2f((unsigned short)(u & 0xffff));
        float f1 = b2f((unsigned short)(u >> 16));
        sl = f0 * alp[lane * 2] + f1 * alp[lane * 2 + 1];
        sr = f0 * arp[lane * 2] + f1 * arp[lane * 2 + 1];
    } else {
        float f0 = b2f(zp[lane]);
        sl = f0 * alp[lane];
        sr = f0 * arp[lane];
    }
    #pragma unroll
    for (int o = 32; o; o >>= 1) {
        sl += __shfl_xor(sl, o);
        sr += __shfl_xor(sr, o);
    }
    if (lane == 0) { el[wid] = sl; er[wid] = sr; }
}

// --------------- CSR build ---------------------------------------------------
__global__ void hist_k(const int* __restrict__ dst, int* __restrict__ cnt)
{
    int i = blockIdx.x * blockDim.x + threadIdx.x;
    if (i < EE) atomicAdd(&cnt[dst[i]], 1);
}

__global__ __launch_bounds__(1024) void scan_k(const int* __restrict__ cnt,
                                               int* __restrict__ offs)
{
    __shared__ int part[1024];
    int t = threadIdx.x;
    const int per = (NN + 1023) / 1024;
    int beg = t * per, end = min(beg + per, NN);
    int sum = 0;
    for (int i = beg; i < end; ++i) sum += cnt[i];
    part[t] = sum;
    __syncthreads();
    for (int off = 1; off < 1024; off <<= 1) {
        int add = (t >= off) ? part[t - off] : 0;
        __syncthreads();
        part[t] += add;
        __syncthreads();
    }
    int run = (t == 0) ? 0 : part[t - 1];
    for (int i = beg; i < end; ++i) { offs[i] = run; run += cnt[i]; }
    if (t == 0) offs[NN] = part[1023];
}

__global__ void scatter_k(const int* __restrict__ src, const int* __restrict__ dst,
                          const int* __restrict__ offs, int* __restrict__ cursor,
                          int* __restrict__ srcs_sorted)
{
    int i = blockIdx.x * blockDim.x + threadIdx.x;
    if (i >= EE) return;
    int d = dst[i];
    int p = offs[d] + atomicAdd(&cursor[d], 1);
    srcs_sorted[p] = src[i];
}

// --------------- GAT aggregation: one wave per dst node, ALL heads -----------
// Single pass (no max-subtract: logits bounded by data scale; softmax is
// shift-invariant so result matches reference to fp32 rounding).
template<int D, bool MEAN>
__global__ __launch_bounds__(256) void agg2_k(
    const unsigned short* __restrict__ zb, const float* __restrict__ el,
    const float* __restrict__ er, const int* __restrict__ offs,
    const int* __restrict__ srcs, const float* __restrict__ bias,
    unsigned short* __restrict__ outb, float* __restrict__ outf)
{
    constexpr int HD  = HH * D;
    constexpr int EPL = HD / 64;          // 8 for D=128, 4 for D=64
    int n = blockIdx.x * 4 + (threadIdx.x >> 6);
    if (n >= NN) return;
    int lane = threadIdx.x & 63;
    int h = lane >> 4;
    int beg = offs[n], end = offs[n + 1];
    float erh = er[n * HH + h];

    float acc[EPL] = {};
    float wsum = 0.f;
    for (int e = beg; e < end; ++e) {
        int s = srcs[e];
        float x = el[s * HH + h] + erh;
        x = x >= 0.f ? x : 0.2f * x;
        float ex = __expf(x);
        wsum += ex;
        if (D == 128) {
            ushort8v v = *reinterpret_cast<const ushort8v*>(
                &zb[(size_t)s * HD + lane * EPL]);
            #pragma unroll
            for (int j = 0; j < EPL; ++j)
                acc[j] = fmaf(ex, b2f(v[j]), acc[j]);
        } else {
            ushort4v v = *reinterpret_cast<const ushort4v*>(
                &zb[(size_t)s * HD + lane * EPL]);
            #pragma unroll
            for (int j = 0; j < EPL; ++j)
                acc[j] = fmaf(ex, b2f(v[j]), acc[j]);
        }
    }
    float inv = wsum > 0.f ? 1.f / wsum : 0.f;

    float vv[EPL];
    #pragma unroll
    for (int j = 0; j < EPL; ++j) {
        float v = acc[j] * inv + bias[h * D + (lane & 15) * EPL + j];
        vv[j] = v >= 0.f ? v : 0.01f * v;
    }

    if (!MEAN) {
        ushort8v u;
        #pragma unroll
        for (int j = 0; j < EPL && j < 8; ++j) u[j] = f2b(vv[j]);
        *reinterpret_cast<ushort8v*>(&outb[(size_t)n * HD + lane * EPL]) = u;
    } else {
        #pragma unroll
        for (int j = 0; j < EPL; ++j) {
            float s = vv[j];
            s += __shfl_xor(s, 16);
            s += __shfl_xor(s, 32);
            s *= 0.25f;
            vv[j] = s >= 0.f ? s : 0.01f * s;
        }
        if (lane < 16) {
            float* op = outf + (size_t)n * D + lane * EPL;
            #pragma unroll
            for (int j = 0; j < EPL; j += 4)
                *reinterpret_cast<float4*>(op + j) =
                    make_float4(vv[j], vv[j + 1], vv[j + 2], vv[j + 3]);
        }
    }
}

// -----------------------------------------------------------------------------
extern "C" void kernel_launch(void* const* d_in, const int* in_sizes, int n_in,
                              void* d_out, int out_size, void* d_ws, size_t ws_size,
                              hipStream_t stream)
{
    const float* n_feat = (const float*)d_in[0];
    const int*   src    = (const int*)d_in[1];
    const int*   dst    = (const int*)d_in[2];
    const float* g0_W  = (const float*)d_in[3];
    const float* g0_al = (const float*)d_in[4];
    const float* g0_ar = (const float*)d_in[5];
    const float* g0_b  = (const float*)d_in[6];
    const float* d0_W  = (const float*)d_in[7];
    const float* d0_b  = (const float*)d_in[8];
    const float* g1_W  = (const float*)d_in[9];
    const float* g1_al = (const float*)d_in[10];
    const float* g1_ar = (const float*)d_in[11];
    const float* g1_b  = (const float*)d_in[12];
    const float* d1_W  = (const float*)d_in[13];
    const float* d1_b  = (const float*)d_in[14];
    const float* g2_W  = (const float*)d_in[15];
    const float* g2_al = (const float*)d_in[16];
    const float* g2_ar = (const float*)d_in[17];
    const float* g2_b  = (const float*)d_in[18];

    char* ws = (char*)d_ws;
    size_t off = 0;
    auto alloc = [&](size_t bytes) {
        void* p = ws + off;
        off += (bytes + 255) & ~(size_t)255;
        return p;
    };
    // All-bf16 activation pipeline. Total ~135 MB (budget: 236 MB known-good).
    unsigned short* zB   = (unsigned short*)alloc((size_t)NN * 512 * 2); // proj out
    unsigned short* hB   = (unsigned short*)alloc((size_t)NN * 512 * 2); // agg out
    unsigned short* hC   = (unsigned short*)alloc((size_t)NN * 128 * 2); // dense out
    unsigned short* xF   = (unsigned short*)alloc((size_t)NN * 128 * 2); // n_feat bf16
    unsigned short* g0t  = (unsigned short*)alloc(512 * 128 * 2);
    unsigned short* g1t  = (unsigned short*)alloc(512 * 128 * 2);
    unsigned short* g2t  = (unsigned short*)alloc(256 * 128 * 2);
    unsigned short* d0t  = (unsigned short*)alloc(128 * 512 * 2);
    unsigned short* d1t  = (unsigned short*)alloc(128 * 512 * 2);
    float*          el   = (float*)alloc((size_t)NN * HH * 4);
    float*          er   = (float*)alloc((size_t)NN * HH * 4);
    int*            cnt  = (int*)alloc((size_t)NN * 4);
    int*            curs = (int*)alloc((size_t)NN * 4);
    int*            offs = (int*)alloc((size_t)(NN + 1) * 4);
    int*            srcs = (int*)alloc((size_t)EE * 4);

    // ---- prep: CSR build + weight/feature casts ----
    hipMemsetAsync(cnt, 0, (size_t)NN * 4, stream);
    hipMemsetAsync(curs, 0, (size_t)NN * 4, stream);
    hist_k<<<(EE + 255) / 256, 256, 0, stream>>>(dst, cnt);
    scan_k<<<1, 1024, 0, stream>>>(cnt, offs);
    scatter_k<<<(EE + 255) / 256, 256, 0, stream>>>(src, dst, offs, curs, srcs);

    cast_k<<<(NN * 128 / 4 + 255) / 256, 256, 0, stream>>>(n_feat, xF, NN * 128 / 4);
    cast_k<<<(128 * 512 / 4 + 255) / 256, 256, 0, stream>>>(d0_W, d0t, 128 * 512 / 4);
    cast_k<<<(128 * 512 / 4 + 255) / 256, 256, 0, stream>>>(d1_W, d1t, 128 * 512 / 4);
    tr_k<<<(128 * 512 + 255) / 256, 256, 0, stream>>>(g0_W, g0t, 128, 512);
    tr_k<<<(128 * 512 + 255) / 256, 256, 0, stream>>>(g1_W, g1t, 128, 512);
    tr_k<<<(128 * 256 + 255) / 256, 256, 0, stream>>>(g2_W, g2t, 128, 256);

    const int MT   = (NN + 63) / 64;       // 782 row tiles
    const int WAVB = (NN * HH + 3) / 4;
    const int NODB = (NN + 3) / 4;

    // ---- layer 0 ----
    mgemm_k<false><<<dim3(4, MT), 256, 0, stream>>>(xF, g0t, nullptr, zB,
                                                    NN, 512, 128, 0.f);
    elrb_k<128><<<WAVB, 256, 0, stream>>>(zB, g0_al, g0_ar, el, er);
    agg2_k<128, false><<<NODB, 256, 0, stream>>>(zB, el, er, offs, srcs, g0_b,
                                                 hB, nullptr);
    mgemm_k<true><<<dim3(1, MT), 256, 0, stream>>>(hB, d0t, d0_b, hC,
                                                   NN, 128, 512, 0.01f);

    // ---- layer 1 ----
    mgemm_k<false><<<dim3(4, MT), 256, 0, stream>>>(hC, g1t, nullptr, zB,
                                                    NN, 512, 128, 0.f);
    elrb_k<128><<<WAVB, 256, 0, stream>>>(zB, g1_al, g1_ar, el, er);
    agg2_k<128, false><<<NODB, 256, 0, stream>>>(zB, el, er, offs, srcs, g1_b,
                                                 hB, nullptr);
    mgemm_k<true><<<dim3(1, MT), 256, 0, stream>>>(hB, d1t, d1_b, hC,
                                                   NN, 128, 512, 0.01f);

    // ---- layer 2 + fused bias/lrelu/mean/lrelu ----
    mgemm_k<false><<<dim3(2, MT), 256, 0, stream>>>(hC, g2t, nullptr, zB,
                                                    NN, 256, 128, 0.f);
    elrb_k<64><<<WAVB, 256, 0, stream>>>(zB, g2_al, g2_ar, el, er);
    agg2_k<64, true><<<NODB, 256, 0, stream>>>(zB, el, er, offs, srcs, g2_b,
                                               nullptr, (float*)d_out);
}

// Round 5
// 572.580 us; speedup vs baseline: 3.4657x; 1.2564x over previous
//
#include <hip/hip_runtime.h>

#define NN 50000
#define EE 800000
#define HH 4

typedef __attribute__((ext_vector_type(8))) short short8v;     // 8 bf16 = 4 VGPR
typedef __attribute__((ext_vector_type(4))) float f32x4;
typedef __attribute__((ext_vector_type(8))) unsigned short ushort8v;
typedef __attribute__((ext_vector_type(4))) unsigned short ushort4v;

__device__ __forceinline__ float b2f(unsigned short u) {
    return __uint_as_float(((unsigned int)u) << 16);
}
__device__ __forceinline__ unsigned short f2b(float f) {
    unsigned int x = __float_as_uint(f);
    x += 0x7fffu + ((x >> 16) & 1u);
    return (unsigned short)(x >> 16);
}

// ---------------- bf16 MFMA GEMM: C[M,N] = A[M,K] @ Bt[N,K]^T ---------------
// BM=64, BN=128, BK=64; 256 threads = 4 waves; wave w owns rows w*16..w*16+15.
// WEL=1: BN==D==128, block cols = one head -> fused el/er epilogue.
// WEL=2: D=64, block cols = two heads.
template<bool ACT, int WEL>
__global__ __launch_bounds__(256) void mgemm_k(
    const unsigned short* __restrict__ A, const unsigned short* __restrict__ Bt,
    const float* __restrict__ bias, unsigned short* __restrict__ C,
    const float* __restrict__ al, const float* __restrict__ ar,
    float* __restrict__ el, float* __restrict__ er,
    int M, int N, int K, float slope)
{
    __shared__ unsigned short As[64 * 72];    // 72 = 64 + 8 pad (16B-aligned rows)
    __shared__ unsigned short Bs[128 * 72];
    const int t   = threadIdx.x;
    const int m0  = blockIdx.y * 64;
    const int n0  = blockIdx.x * 128;
    const int w16 = (t >> 6) * 16;
    const int l   = t & 63;
    const int lr  = l & 15;            // frag row (A) / col (B,C)
    const int lk8 = (l >> 4) * 8;      // frag k-offset

    f32x4 acc[8];
    #pragma unroll
    for (int i = 0; i < 8; ++i) acc[i] = (f32x4)0.f;

    for (int k0 = 0; k0 < K; k0 += 64) {
        #pragma unroll
        for (int cc = 0; cc < 2; ++cc) {   // stage A: 64x64, 8-elem chunks
            int c = t + cc * 256;
            int row = c >> 3, seg = (c & 7) * 8;
            int gm = m0 + row;
            short8v v = (short8v)0;
            if (gm < M)
                v = *reinterpret_cast<const short8v*>(&A[(size_t)gm * K + k0 + seg]);
            *reinterpret_cast<short8v*>(&As[row * 72 + seg]) = v;
        }
        #pragma unroll
        for (int cc = 0; cc < 4; ++cc) {   // stage B: 128x64
            int c = t + cc * 256;
            int row = c >> 3, seg = (c & 7) * 8;
            short8v v = *reinterpret_cast<const short8v*>(
                &Bt[(size_t)(n0 + row) * K + k0 + seg]);
            *reinterpret_cast<short8v*>(&Bs[row * 72 + seg]) = v;
        }
        __syncthreads();
        #pragma unroll
        for (int kk = 0; kk < 64; kk += 32) {
            short8v a = *reinterpret_cast<const short8v*>(
                &As[(w16 + lr) * 72 + kk + lk8]);
            #pragma unroll
            for (int nb = 0; nb < 8; ++nb) {
                short8v b = *reinterpret_cast<const short8v*>(
                    &Bs[(nb * 16 + lr) * 72 + kk + lk8]);
                acc[nb] = __builtin_amdgcn_mfma_f32_16x16x32_bf16(a, b, acc[nb], 0, 0, 0);
            }
        }
        __syncthreads();
    }

    // ---- fused el/er: dot acc rows with al/ar over this block's head cols ----
    if (WEL > 0) {
        const int nbh = (WEL == 1) ? 8 : 4;     // nb per head
        const int Dd  = (WEL == 1) ? 128 : 64;
        #pragma unroll
        for (int hh = 0; hh < WEL; ++hh) {
            int head = (WEL == 1) ? blockIdx.x : blockIdx.x * 2 + hh;
            float pl[4] = {}, pr[4] = {};
            #pragma unroll
            for (int nb = 0; nb < nbh; ++nb) {
                float alv = al[head * Dd + nb * 16 + lr];
                float arv = ar[head * Dd + nb * 16 + lr];
                #pragma unroll
                for (int r = 0; r < 4; ++r) {
                    float z = acc[hh * nbh + nb][r];
                    pl[r] = fmaf(z, alv, pl[r]);
                    pr[r] = fmaf(z, arv, pr[r]);
                }
            }
            #pragma unroll
            for (int r = 0; r < 4; ++r) {
                #pragma unroll
                for (int o = 1; o < 16; o <<= 1) {
                    pl[r] += __shfl_xor(pl[r], o);
                    pr[r] += __shfl_xor(pr[r], o);
                }
            }
            if (lr == 0) {
                #pragma unroll
                for (int r = 0; r < 4; ++r) {
                    int gm = m0 + w16 + (l >> 4) * 4 + r;
                    if (gm < M) {
                        el[gm * HH + head] = pl[r];
                        er[gm * HH + head] = pr[r];
                    }
                }
            }
        }
    }

    #pragma unroll
    for (int nb = 0; nb < 8; ++nb) {
        #pragma unroll
        for (int r = 0; r < 4; ++r) {
            int gm = m0 + w16 + (l >> 4) * 4 + r;
            int gn = n0 + nb * 16 + lr;
            if (gm < M) {
                float v = acc[nb][r];
                if (ACT) { v += bias[gn]; v = v >= 0.f ? v : slope * v; }
                C[(size_t)gm * N + gn] = f2b(v);
            }
        }
    }
}

// ---------------- weight prep: transpose-cast / cast -------------------------
__global__ void tr_k(const float* __restrict__ W, unsigned short* __restrict__ Wt,
                     int K, int N)
{
    int idx = blockIdx.x * blockDim.x + threadIdx.x;
    if (idx >= K * N) return;
    int n = idx / K, k = idx - n * K;
    Wt[idx] = f2b(W[(size_t)k * N + n]);
}

__global__ void cast_k(const float* __restrict__ x, unsigned short* __restrict__ y,
                       int n4)
{
    int i = blockIdx.x * blockDim.x + threadIdx.x;
    if (i >= n4) return;
    float4 v = reinterpret_cast<const float4*>(x)[i];
    ushort4v u;
    u[0] = f2b(v.x); u[1] = f2b(v.y); u[2] = f2b(v.z); u[3] = f2b(v.w);
    reinterpret_cast<ushort4v*>(y)[i] = u;
}

// --------------- CSR build ---------------------------------------------------
__global__ void hist_k(const int* __restrict__ dst, int* __restrict__ cnt)
{
    int i = blockIdx.x * blockDim.x + threadIdx.x;
    if (i < EE) atomicAdd(&cnt[dst[i]], 1);
}

// 3-stage parallel exclusive scan of cnt[NN] -> offs[NN+1]
#define SCAN_B 196   // ceil(50000/256)
__global__ __launch_bounds__(256) void scan1_k(const int* __restrict__ cnt,
                                               int* __restrict__ offs,
                                               int* __restrict__ bsum)
{
    __shared__ int sh[256];
    int b = blockIdx.x, t = threadIdx.x, i = b * 256 + t;
    int v = (i < NN) ? cnt[i] : 0;
    sh[t] = v;
    __syncthreads();
    int pre = 0;                       // exclusive prefix within block
    #pragma unroll
    for (int o = 1; o < 256; o <<= 1) {
        int add = (t >= o) ? sh[t - o] : 0;
        __syncthreads();
        sh[t] += add;
        __syncthreads();
    }
    pre = sh[t] - v;                   // inclusive - self = exclusive
    if (i < NN) offs[i] = pre;
    if (t == 255) bsum[b] = sh[t];
}

__global__ __launch_bounds__(256) void scan2_k(int* __restrict__ bsum)
{
    __shared__ int sh[256];
    int t = threadIdx.x;
    int v = (t < SCAN_B) ? bsum[t] : 0;
    sh[t] = v;
    __syncthreads();
    #pragma unroll
    for (int o = 1; o < 256; o <<= 1) {
        int add = (t >= o) ? sh[t - o] : 0;
        __syncthreads();
        sh[t] += add;
        __syncthreads();
    }
    if (t < SCAN_B) bsum[t] = sh[t] - v;   // exclusive block prefix
}

__global__ __launch_bounds__(256) void scan3_k(int* __restrict__ offs,
                                               const int* __restrict__ bsum)
{
    int b = blockIdx.x, t = threadIdx.x, i = b * 256 + t;
    if (i < NN) offs[i] += bsum[b];
    if (i == NN - 1) offs[NN] = EE;
}

__global__ void scatter_k(const int* __restrict__ src, const int* __restrict__ dst,
                          const int* __restrict__ offs, int* __restrict__ cursor,
                          int* __restrict__ srcs_sorted)
{
    int i = blockIdx.x * blockDim.x + threadIdx.x;
    if (i >= EE) return;
    int d = dst[i];
    int p = offs[d] + atomicAdd(&cursor[d], 1);
    srcs_sorted[p] = src[i];
}

// --------------- GAT aggregation: one wave per dst node, ALL heads -----------
// Single pass (softmax is shift-invariant; logits bounded by data scale).
// 2-deep manual prefetch on the edge loop.
template<int D, bool MEAN>
__global__ __launch_bounds__(256) void agg2_k(
    const unsigned short* __restrict__ zb, const float* __restrict__ el,
    const float* __restrict__ er, const int* __restrict__ offs,
    const int* __restrict__ srcs, const float* __restrict__ bias,
    unsigned short* __restrict__ outb, float* __restrict__ outf)
{
    constexpr int HD  = HH * D;
    constexpr int EPL = HD / 64;          // 8 for D=128, 4 for D=64
    typedef __attribute__((ext_vector_type(EPL))) unsigned short uvec;
    int n = blockIdx.x * 4 + (threadIdx.x >> 6);
    if (n >= NN) return;
    int lane = threadIdx.x & 63;
    int h = lane >> 4;
    int beg = offs[n], end = offs[n + 1];
    float erh = er[n * HH + h];

    float acc[EPL] = {};
    float wsum = 0.f;
    if (beg < end) {
        int s = srcs[beg];
        float elv = el[s * HH + h];
        uvec v = *reinterpret_cast<const uvec*>(&zb[(size_t)s * HD + lane * EPL]);
        for (int e = beg; e < end; ++e) {
            int en = (e + 1 < end) ? e + 1 : e;     // branchless clamp
            int s2 = srcs[en];
            float elv2 = el[s2 * HH + h];
            uvec v2 = *reinterpret_cast<const uvec*>(&zb[(size_t)s2 * HD + lane * EPL]);
            float x = elv + erh;
            x = x >= 0.f ? x : 0.2f * x;
            float ex = __expf(x);
            wsum += ex;
            #pragma unroll
            for (int j = 0; j < EPL; ++j)
                acc[j] = fmaf(ex, b2f(v[j]), acc[j]);
            elv = elv2;
            v = v2;
        }
    }
    float inv = wsum > 0.f ? 1.f / wsum : 0.f;

    float vv[EPL];
    #pragma unroll
    for (int j = 0; j < EPL; ++j) {
        float v = acc[j] * inv + bias[h * D + (lane & 15) * EPL + j];
        vv[j] = v >= 0.f ? v : 0.01f * v;
    }

    if (!MEAN) {
        uvec u;
        #pragma unroll
        for (int j = 0; j < EPL; ++j) u[j] = f2b(vv[j]);
        *reinterpret_cast<uvec*>(&outb[(size_t)n * HD + lane * EPL]) = u;
    } else {
        #pragma unroll
        for (int j = 0; j < EPL; ++j) {
            float s = vv[j];
            s += __shfl_xor(s, 16);
            s += __shfl_xor(s, 32);
            s *= 0.25f;
            vv[j] = s >= 0.f ? s : 0.01f * s;
        }
        if (lane < 16) {
            float* op = outf + (size_t)n * D + lane * EPL;
            #pragma unroll
            for (int j = 0; j < EPL; j += 4)
                *reinterpret_cast<float4*>(op + j) =
                    make_float4(vv[j], vv[j + 1], vv[j + 2], vv[j + 3]);
        }
    }
}

// -----------------------------------------------------------------------------
extern "C" void kernel_launch(void* const* d_in, const int* in_sizes, int n_in,
                              void* d_out, int out_size, void* d_ws, size_t ws_size,
                              hipStream_t stream)
{
    const float* n_feat = (const float*)d_in[0];
    const int*   src    = (const int*)d_in[1];
    const int*   dst    = (const int*)d_in[2];
    const float* g0_W  = (const float*)d_in[3];
    const float* g0_al = (const float*)d_in[4];
    const float* g0_ar = (const float*)d_in[5];
    const float* g0_b  = (const float*)d_in[6];
    const float* d0_W  = (const float*)d_in[7];
    const float* d0_b  = (const float*)d_in[8];
    const float* g1_W  = (const float*)d_in[9];
    const float* g1_al = (const float*)d_in[10];
    const float* g1_ar = (const float*)d_in[11];
    const float* g1_b  = (const float*)d_in[12];
    const float* d1_W  = (const float*)d_in[13];
    const float* d1_b  = (const float*)d_in[14];
    const float* g2_W  = (const float*)d_in[15];
    const float* g2_al = (const float*)d_in[16];
    const float* g2_ar = (const float*)d_in[17];
    const float* g2_b  = (const float*)d_in[18];

    char* ws = (char*)d_ws;
    size_t off = 0;
    auto alloc = [&](size_t bytes) {
        void* p = ws + off;
        off += (bytes + 255) & ~(size_t)255;
        return p;
    };
    // Total ~135 MB (budget: 236 MB known-good).
    unsigned short* zB   = (unsigned short*)alloc((size_t)NN * 512 * 2); // proj out
    unsigned short* hB   = (unsigned short*)alloc((size_t)NN * 512 * 2); // agg out
    unsigned short* hC   = (unsigned short*)alloc((size_t)NN * 128 * 2); // dense out
    unsigned short* xF   = (unsigned short*)alloc((size_t)NN * 128 * 2); // n_feat bf16
    unsigned short* g0t  = (unsigned short*)alloc(512 * 128 * 2);
    unsigned short* g1t  = (unsigned short*)alloc(512 * 128 * 2);
    unsigned short* g2t  = (unsigned short*)alloc(256 * 128 * 2);
    unsigned short* d0t  = (unsigned short*)alloc(128 * 512 * 2);
    unsigned short* d1t  = (unsigned short*)alloc(128 * 512 * 2);
    float*          el   = (float*)alloc((size_t)NN * HH * 4);
    float*          er   = (float*)alloc((size_t)NN * HH * 4);
    int*            cnt  = (int*)alloc((size_t)NN * 4);
    int*            curs = (int*)alloc((size_t)NN * 4);
    int*            offs = (int*)alloc((size_t)(NN + 1) * 4);
    int*            srcs = (int*)alloc((size_t)EE * 4);
    int*            bsum = (int*)alloc(256 * 4);

    // ---- prep: CSR build + weight/feature casts ----
    hipMemsetAsync(cnt, 0, (size_t)NN * 4, stream);
    hipMemsetAsync(curs, 0, (size_t)NN * 4, stream);
    hist_k<<<(EE + 255) / 256, 256, 0, stream>>>(dst, cnt);
    scan1_k<<<SCAN_B, 256, 0, stream>>>(cnt, offs, bsum);
    scan2_k<<<1, 256, 0, stream>>>(bsum);
    scan3_k<<<SCAN_B, 256, 0, stream>>>(offs, bsum);
    scatter_k<<<(EE + 255) / 256, 256, 0, stream>>>(src, dst, offs, curs, srcs);

    cast_k<<<(NN * 128 / 4 + 255) / 256, 256, 0, stream>>>(n_feat, xF, NN * 128 / 4);
    cast_k<<<(128 * 512 / 4 + 255) / 256, 256, 0, stream>>>(d0_W, d0t, 128 * 512 / 4);
    cast_k<<<(128 * 512 / 4 + 255) / 256, 256, 0, stream>>>(d1_W, d1t, 128 * 512 / 4);
    tr_k<<<(128 * 512 + 255) / 256, 256, 0, stream>>>(g0_W, g0t, 128, 512);
    tr_k<<<(128 * 512 + 255) / 256, 256, 0, stream>>>(g1_W, g1t, 128, 512);
    tr_k<<<(128 * 256 + 255) / 256, 256, 0, stream>>>(g2_W, g2t, 128, 256);

    const int MT   = (NN + 63) / 64;       // 782 row tiles
    const int NODB = (NN + 3) / 4;

    // ---- layer 0 ----
    mgemm_k<false, 1><<<dim3(4, MT), 256, 0, stream>>>(
        xF, g0t, nullptr, zB, g0_al, g0_ar, el, er, NN, 512, 128, 0.f);
    agg2_k<128, false><<<NODB, 256, 0, stream>>>(zB, el, er, offs, srcs, g0_b,
                                                 hB, nullptr);
    mgemm_k<true, 0><<<dim3(1, MT), 256, 0, stream>>>(
        hB, d0t, d0_b, hC, nullptr, nullptr, nullptr, nullptr, NN, 128, 512, 0.01f);

    // ---- layer 1 ----
    mgemm_k<false, 1><<<dim3(4, MT), 256, 0, stream>>>(
        hC, g1t, nullptr, zB, g1_al, g1_ar, el, er, NN, 512, 128, 0.f);
    agg2_k<128, false><<<NODB, 256, 0, stream>>>(zB, el, er, offs, srcs, g1_b,
                                                 hB, nullptr);
    mgemm_k<true, 0><<<dim3(1, MT), 256, 0, stream>>>(
        hB, d1t, d1_b, hC, nullptr, nullptr, nullptr, nullptr, NN, 128, 512, 0.01f);

    // ---- layer 2 + fused bias/lrelu/mean/lrelu ----
    mgemm_k<false, 2><<<dim3(2, MT), 256, 0, stream>>>(
        hC, g2t, nullptr, zB, g2_al, g2_ar, el, er, NN, 256, 128, 0.f);
    agg2_k<64, true><<<NODB, 256, 0, stream>>>(zB, el, er, offs, srcs, g2_b,
                                               nullptr, (float*)d_out);
}

// Round 6
// 570.724 us; speedup vs baseline: 3.4770x; 1.0033x over previous
//
#include <hip/hip_runtime.h>

#define NN 50000
#define EE 800000
#define HH 4

typedef __attribute__((ext_vector_type(8))) short short8v;     // 8 bf16 = 4 VGPR
typedef __attribute__((ext_vector_type(4))) float f32x4;
typedef __attribute__((ext_vector_type(8))) unsigned short ushort8v;
typedef __attribute__((ext_vector_type(4))) unsigned short ushort4v;

__device__ __forceinline__ float b2f(unsigned short u) {
    return __uint_as_float(((unsigned int)u) << 16);
}
__device__ __forceinline__ unsigned short f2b(float f) {
    unsigned int x = __float_as_uint(f);
    x += 0x7fffu + ((x >> 16) & 1u);
    return (unsigned short)(x >> 16);
}

// ---------------- bf16 MFMA GEMM: C[M,N] = A[M,K] @ Bt[N,K]^T ---------------
// BM=64*WR, BN=128, BK=64; 256 threads = 4 waves; wave w owns rows
// [w*16*WR, (w+1)*16*WR).  WR=2 doubles MFMA per staged byte (proj GEMMs).
// WEL=1: BN==D==128, block cols = one head -> fused el/er epilogue.
// WEL=2: D=64, block cols = two heads.
template<int WR, bool ACT, int WEL>
__global__ __launch_bounds__(256) void mgemm_k(
    const unsigned short* __restrict__ A, const unsigned short* __restrict__ Bt,
    const float* __restrict__ bias, unsigned short* __restrict__ C,
    const float* __restrict__ al, const float* __restrict__ ar,
    float* __restrict__ el, float* __restrict__ er,
    int M, int N, int K, float slope)
{
    constexpr int BM = 64 * WR;
    __shared__ unsigned short As[BM * 72];    // 72 = 64 + 8 pad
    __shared__ unsigned short Bs[128 * 72];
    const int t   = threadIdx.x;
    const int m0  = blockIdx.y * BM;
    const int n0  = blockIdx.x * 128;
    const int w   = t >> 6;
    const int l   = t & 63;
    const int lr  = l & 15;            // frag row (A) / col (B,C)
    const int lk8 = (l >> 4) * 8;      // frag k-offset
    const int wbase = w * 16 * WR;

    f32x4 acc[WR][8];
    #pragma unroll
    for (int rr = 0; rr < WR; ++rr)
        #pragma unroll
        for (int i = 0; i < 8; ++i) acc[rr][i] = (f32x4)0.f;

    for (int k0 = 0; k0 < K; k0 += 64) {
        #pragma unroll
        for (int cc = 0; cc < 2 * WR; ++cc) {   // stage A: BMx64, 8-elem chunks
            int c = t + cc * 256;
            int row = c >> 3, seg = (c & 7) * 8;
            int gm = m0 + row;
            short8v v = (short8v)0;
            if (gm < M)
                v = *reinterpret_cast<const short8v*>(&A[(size_t)gm * K + k0 + seg]);
            *reinterpret_cast<short8v*>(&As[row * 72 + seg]) = v;
        }
        #pragma unroll
        for (int cc = 0; cc < 4; ++cc) {   // stage B: 128x64
            int c = t + cc * 256;
            int row = c >> 3, seg = (c & 7) * 8;
            short8v v = *reinterpret_cast<const short8v*>(
                &Bt[(size_t)(n0 + row) * K + k0 + seg]);
            *reinterpret_cast<short8v*>(&Bs[row * 72 + seg]) = v;
        }
        __syncthreads();
        #pragma unroll
        for (int kk = 0; kk < 64; kk += 32) {
            short8v a[WR];
            #pragma unroll
            for (int rr = 0; rr < WR; ++rr)
                a[rr] = *reinterpret_cast<const short8v*>(
                    &As[(wbase + rr * 16 + lr) * 72 + kk + lk8]);
            #pragma unroll
            for (int nb = 0; nb < 8; ++nb) {
                short8v b = *reinterpret_cast<const short8v*>(
                    &Bs[(nb * 16 + lr) * 72 + kk + lk8]);
                #pragma unroll
                for (int rr = 0; rr < WR; ++rr)
                    acc[rr][nb] = __builtin_amdgcn_mfma_f32_16x16x32_bf16(
                        a[rr], b, acc[rr][nb], 0, 0, 0);
            }
        }
        __syncthreads();
    }

    // ---- fused el/er: dot acc rows with al/ar over this block's head cols ----
    if (WEL > 0) {
        const int nbh = (WEL == 1) ? 8 : 4;     // nb per head
        const int Dd  = (WEL == 1) ? 128 : 64;
        #pragma unroll
        for (int hh = 0; hh < WEL; ++hh) {
            int head = (WEL == 1) ? blockIdx.x : blockIdx.x * 2 + hh;
            #pragma unroll
            for (int rr = 0; rr < WR; ++rr) {
                float pl[4] = {}, pr[4] = {};
                #pragma unroll
                for (int nb = 0; nb < nbh; ++nb) {
                    float alv = al[head * Dd + nb * 16 + lr];
                    float arv = ar[head * Dd + nb * 16 + lr];
                    #pragma unroll
                    for (int r = 0; r < 4; ++r) {
                        float z = acc[rr][hh * nbh + nb][r];
                        pl[r] = fmaf(z, alv, pl[r]);
                        pr[r] = fmaf(z, arv, pr[r]);
                    }
                }
                #pragma unroll
                for (int r = 0; r < 4; ++r) {
                    #pragma unroll
                    for (int o = 1; o < 16; o <<= 1) {
                        pl[r] += __shfl_xor(pl[r], o);
                        pr[r] += __shfl_xor(pr[r], o);
                    }
                }
                if (lr == 0) {
                    #pragma unroll
                    for (int r = 0; r < 4; ++r) {
                        int gm = m0 + wbase + rr * 16 + (l >> 4) * 4 + r;
                        if (gm < M) {
                            el[gm * HH + head] = pl[r];
                            er[gm * HH + head] = pr[r];
                        }
                    }
                }
            }
        }
    }

    #pragma unroll
    for (int rr = 0; rr < WR; ++rr) {
        #pragma unroll
        for (int nb = 0; nb < 8; ++nb) {
            #pragma unroll
            for (int r = 0; r < 4; ++r) {
                int gm = m0 + wbase + rr * 16 + (l >> 4) * 4 + r;
                int gn = n0 + nb * 16 + lr;
                if (gm < M) {
                    float v = acc[rr][nb][r];
                    if (ACT) { v += bias[gn]; v = v >= 0.f ? v : slope * v; }
                    C[(size_t)gm * N + gn] = f2b(v);
                }
            }
        }
    }
}

// ---------------- weight prep: transpose-cast / cast -------------------------
__global__ void tr_k(const float* __restrict__ W, unsigned short* __restrict__ Wt,
                     int K, int N)
{
    int idx = blockIdx.x * blockDim.x + threadIdx.x;
    if (idx >= K * N) return;
    int n = idx / K, k = idx - n * K;
    Wt[idx] = f2b(W[(size_t)k * N + n]);
}

__global__ void cast_k(const float* __restrict__ x, unsigned short* __restrict__ y,
                       int n4)
{
    int i = blockIdx.x * blockDim.x + threadIdx.x;
    if (i >= n4) return;
    float4 v = reinterpret_cast<const float4*>(x)[i];
    ushort4v u;
    u[0] = f2b(v.x); u[1] = f2b(v.y); u[2] = f2b(v.z); u[3] = f2b(v.w);
    reinterpret_cast<ushort4v*>(y)[i] = u;
}

// --------------- CSR build ---------------------------------------------------
__global__ void hist_k(const int* __restrict__ dst, int* __restrict__ cnt)
{
    int i = blockIdx.x * blockDim.x + threadIdx.x;
    if (i < EE) atomicAdd(&cnt[dst[i]], 1);
}

// 3-stage parallel exclusive scan of cnt[NN] -> offs[NN+1]
#define SCAN_B 196   // ceil(50000/256)
__global__ __launch_bounds__(256) void scan1_k(const int* __restrict__ cnt,
                                               int* __restrict__ offs,
                                               int* __restrict__ bsum)
{
    __shared__ int sh[256];
    int b = blockIdx.x, t = threadIdx.x, i = b * 256 + t;
    int v = (i < NN) ? cnt[i] : 0;
    sh[t] = v;
    __syncthreads();
    #pragma unroll
    for (int o = 1; o < 256; o <<= 1) {
        int add = (t >= o) ? sh[t - o] : 0;
        __syncthreads();
        sh[t] += add;
        __syncthreads();
    }
    if (i < NN) offs[i] = sh[t] - v;
    if (t == 255) bsum[b] = sh[t];
}

__global__ __launch_bounds__(256) void scan2_k(int* __restrict__ bsum)
{
    __shared__ int sh[256];
    int t = threadIdx.x;
    int v = (t < SCAN_B) ? bsum[t] : 0;
    sh[t] = v;
    __syncthreads();
    #pragma unroll
    for (int o = 1; o < 256; o <<= 1) {
        int add = (t >= o) ? sh[t - o] : 0;
        __syncthreads();
        sh[t] += add;
        __syncthreads();
    }
    if (t < SCAN_B) bsum[t] = sh[t] - v;   // exclusive block prefix
}

__global__ __launch_bounds__(256) void scan3_k(int* __restrict__ offs,
                                               const int* __restrict__ bsum)
{
    int b = blockIdx.x, t = threadIdx.x, i = b * 256 + t;
    if (i < NN) offs[i] += bsum[b];
    if (i == NN - 1) offs[NN] = EE;
}

__global__ void scatter_k(const int* __restrict__ src, const int* __restrict__ dst,
                          const int* __restrict__ offs, int* __restrict__ cursor,
                          int* __restrict__ srcs_sorted)
{
    int i = blockIdx.x * blockDim.x + threadIdx.x;
    if (i >= EE) return;
    int d = dst[i];
    int p = offs[d] + atomicAdd(&cursor[d], 1);
    srcs_sorted[p] = src[i];
}

// --------------- GAT aggregation: one wave per dst node, ALL heads -----------
// Single pass (softmax is shift-invariant; logits bounded by data scale).
// 4-deep statically-indexed prefetch (runtime-indexed vec arrays -> scratch).
template<int D, bool MEAN>
__global__ __launch_bounds__(256) void agg2_k(
    const unsigned short* __restrict__ zb, const float* __restrict__ el,
    const float* __restrict__ er, const int* __restrict__ offs,
    const int* __restrict__ srcs, const float* __restrict__ bias,
    unsigned short* __restrict__ outb, float* __restrict__ outf)
{
    constexpr int HD  = HH * D;
    constexpr int EPL = HD / 64;          // 8 for D=128, 4 for D=64
    typedef __attribute__((ext_vector_type(EPL))) unsigned short uvec;
    int n = blockIdx.x * 4 + (threadIdx.x >> 6);
    if (n >= NN) return;
    int lane = threadIdx.x & 63;
    int h = lane >> 4;
    int beg = offs[n];
    int cnt_e = offs[n + 1] - beg;
    float erh = er[n * HH + h];

    float acc[EPL] = {};
    float wsum = 0.f;

    if (cnt_e > 0) {
        auto LD = [&](int idx, uvec& v, float& elv) {
            int e = idx < cnt_e ? idx : cnt_e - 1;   // wave-uniform clamp
            int s = srcs[beg + e];
            elv = el[s * HH + h];
            v = *reinterpret_cast<const uvec*>(&zb[(size_t)s * HD + lane * EPL]);
        };
        auto PROC = [&](const uvec& v, float elv) {
            float x = elv + erh;
            x = x >= 0.f ? x : 0.2f * x;
            float ex = __expf(x);
            wsum += ex;
            #pragma unroll
            for (int j = 0; j < EPL; ++j)
                acc[j] = fmaf(ex, b2f(v[j]), acc[j]);
        };
        uvec v0, v1, v2, v3;
        float e0, e1, e2, e3;
        LD(0, v0, e0); LD(1, v1, e1); LD(2, v2, e2); LD(3, v3, e3);
        for (int c0 = 0; c0 < cnt_e; c0 += 4) {
            // chunk edges c0..c0+3; prefetch c0+4..c0+7 (clamped, wave-uniform)
            PROC(v0, e0); LD(c0 + 4, v0, e0);
            if (c0 + 1 < cnt_e) { PROC(v1, e1); } LD(c0 + 5, v1, e1);
            if (c0 + 2 < cnt_e) { PROC(v2, e2); } LD(c0 + 6, v2, e2);
            if (c0 + 3 < cnt_e) { PROC(v3, e3); } LD(c0 + 7, v3, e3);
        }
    }
    float inv = wsum > 0.f ? 1.f / wsum : 0.f;

    float vv[EPL];
    #pragma unroll
    for (int j = 0; j < EPL; ++j) {
        float v = acc[j] * inv + bias[h * D + (lane & 15) * EPL + j];
        vv[j] = v >= 0.f ? v : 0.01f * v;
    }

    if (!MEAN) {
        uvec u;
        #pragma unroll
        for (int j = 0; j < EPL; ++j) u[j] = f2b(vv[j]);
        *reinterpret_cast<uvec*>(&outb[(size_t)n * HD + lane * EPL]) = u;
    } else {
        #pragma unroll
        for (int j = 0; j < EPL; ++j) {
            float s = vv[j];
            s += __shfl_xor(s, 16);
            s += __shfl_xor(s, 32);
            s *= 0.25f;
            vv[j] = s >= 0.f ? s : 0.01f * s;
        }
        if (lane < 16) {
            float* op = outf + (size_t)n * D + lane * EPL;
            #pragma unroll
            for (int j = 0; j < EPL; j += 4)
                *reinterpret_cast<float4*>(op + j) =
                    make_float4(vv[j], vv[j + 1], vv[j + 2], vv[j + 3]);
        }
    }
}

// -----------------------------------------------------------------------------
extern "C" void kernel_launch(void* const* d_in, const int* in_sizes, int n_in,
                              void* d_out, int out_size, void* d_ws, size_t ws_size,
                              hipStream_t stream)
{
    const float* n_feat = (const float*)d_in[0];
    const int*   src    = (const int*)d_in[1];
    const int*   dst    = (const int*)d_in[2];
    const float* g0_W  = (const float*)d_in[3];
    const float* g0_al = (const float*)d_in[4];
    const float* g0_ar = (const float*)d_in[5];
    const float* g0_b  = (const float*)d_in[6];
    const float* d0_W  = (const float*)d_in[7];
    const float* d0_b  = (const float*)d_in[8];
    const float* g1_W  = (const float*)d_in[9];
    const float* g1_al = (const float*)d_in[10];
    const float* g1_ar = (const float*)d_in[11];
    const float* g1_b  = (const float*)d_in[12];
    const float* d1_W  = (const float*)d_in[13];
    const float* d1_b  = (const float*)d_in[14];
    const float* g2_W  = (const float*)d_in[15];
    const float* g2_al = (const float*)d_in[16];
    const float* g2_ar = (const float*)d_in[17];
    const float* g2_b  = (const float*)d_in[18];

    char* ws = (char*)d_ws;
    size_t off = 0;
    auto alloc = [&](size_t bytes) {
        void* p = ws + off;
        off += (bytes + 255) & ~(size_t)255;
        return p;
    };
    // Total ~135 MB (budget: 236 MB known-good).
    unsigned short* zB   = (unsigned short*)alloc((size_t)NN * 512 * 2); // proj out
    unsigned short* hB   = (unsigned short*)alloc((size_t)NN * 512 * 2); // agg out
    unsigned short* hC   = (unsigned short*)alloc((size_t)NN * 128 * 2); // dense out
    unsigned short* xF   = (unsigned short*)alloc((size_t)NN * 128 * 2); // n_feat bf16
    unsigned short* g0t  = (unsigned short*)alloc(512 * 128 * 2);
    unsigned short* g1t  = (unsigned short*)alloc(512 * 128 * 2);
    unsigned short* g2t  = (unsigned short*)alloc(256 * 128 * 2);
    unsigned short* d0t  = (unsigned short*)alloc(128 * 512 * 2);
    unsigned short* d1t  = (unsigned short*)alloc(128 * 512 * 2);
    float*          el   = (float*)alloc((size_t)NN * HH * 4);
    float*          er   = (float*)alloc((size_t)NN * HH * 4);
    int*            cnt  = (int*)alloc((size_t)NN * 4);
    int*            curs = (int*)alloc((size_t)NN * 4);
    int*            offs = (int*)alloc((size_t)(NN + 1) * 4);
    int*            srcs = (int*)alloc((size_t)EE * 4);
    int*            bsum = (int*)alloc(256 * 4);

    // ---- prep: CSR build + weight/feature casts ----
    hipMemsetAsync(cnt, 0, (size_t)NN * 4, stream);
    hipMemsetAsync(curs, 0, (size_t)NN * 4, stream);
    hist_k<<<(EE + 255) / 256, 256, 0, stream>>>(dst, cnt);
    scan1_k<<<SCAN_B, 256, 0, stream>>>(cnt, offs, bsum);
    scan2_k<<<1, 256, 0, stream>>>(bsum);
    scan3_k<<<SCAN_B, 256, 0, stream>>>(offs, bsum);
    scatter_k<<<(EE + 255) / 256, 256, 0, stream>>>(src, dst, offs, curs, srcs);

    cast_k<<<(NN * 128 / 4 + 255) / 256, 256, 0, stream>>>(n_feat, xF, NN * 128 / 4);
    cast_k<<<(128 * 512 / 4 + 255) / 256, 256, 0, stream>>>(d0_W, d0t, 128 * 512 / 4);
    cast_k<<<(128 * 512 / 4 + 255) / 256, 256, 0, stream>>>(d1_W, d1t, 128 * 512 / 4);
    tr_k<<<(128 * 512 + 255) / 256, 256, 0, stream>>>(g0_W, g0t, 128, 512);
    tr_k<<<(128 * 512 + 255) / 256, 256, 0, stream>>>(g1_W, g1t, 128, 512);
    tr_k<<<(128 * 256 + 255) / 256, 256, 0, stream>>>(g2_W, g2t, 128, 256);

    const int MT   = (NN + 63) / 64;        // 782 row tiles (WR=1)
    const int MT2  = (NN + 127) / 128;      // 391 row tiles (WR=2)
    const int NODB = (NN + 3) / 4;

    // ---- layer 0 ----
    mgemm_k<2, false, 1><<<dim3(4, MT2), 256, 0, stream>>>(
        xF, g0t, nullptr, zB, g0_al, g0_ar, el, er, NN, 512, 128, 0.f);
    agg2_k<128, false><<<NODB, 256, 0, stream>>>(zB, el, er, offs, srcs, g0_b,
                                                 hB, nullptr);
    mgemm_k<1, true, 0><<<dim3(1, MT), 256, 0, stream>>>(
        hB, d0t, d0_b, hC, nullptr, nullptr, nullptr, nullptr, NN, 128, 512, 0.01f);

    // ---- layer 1 ----
    mgemm_k<2, false, 1><<<dim3(4, MT2), 256, 0, stream>>>(
        hC, g1t, nullptr, zB, g1_al, g1_ar, el, er, NN, 512, 128, 0.f);
    agg2_k<128, false><<<NODB, 256, 0, stream>>>(zB, el, er, offs, srcs, g1_b,
                                                 hB, nullptr);
    mgemm_k<1, true, 0><<<dim3(1, MT), 256, 0, stream>>>(
        hB, d1t, d1_b, hC, nullptr, nullptr, nullptr, nullptr, NN, 128, 512, 0.01f);

    // ---- layer 2 + fused bias/lrelu/mean/lrelu ----
    mgemm_k<2, false, 2><<<dim3(2, MT2), 256, 0, stream>>>(
        hC, g2t, nullptr, zB, g2_al, g2_ar, el, er, NN, 256, 128, 0.f);
    agg2_k<64, true><<<NODB, 256, 0, stream>>>(zB, el, er, offs, srcs, g2_b,
                                               nullptr, (float*)d_out);
}